// Round 10
// baseline (594.273 us; speedup 1.0000x reference)
//
#include <hip/hip_runtime.h>
#include <hip/hip_bf16.h>
#include <stdint.h>

// MHA: B=4, S=2048, D_MODEL=1024, H=16, hd=64.
// Interface: fp32 in / fp32 out. Internal compute: bf16 MFMA.

#define B_  4
#define S_  2048
#define DM  1024
#define H_  16
#define HD  64
#define BH  (B_ * H_)

typedef __attribute__((ext_vector_type(8))) short short8;
typedef __attribute__((ext_vector_type(4))) float f32x4;

union U8 { short8 v; ushort u[8]; };

__device__ __forceinline__ ushort f2bf(float f) {
  union { float f; uint32_t i; } x; x.f = f;
  uint32_t r = (x.i + 0x7FFFu + ((x.i >> 16) & 1u)) >> 16;
  return (ushort)r;
}

// packed f32x2 -> bf16x2 (RNE), gfx950 hw convert; no builtin exists (m240)
__device__ __forceinline__ uint32_t cvt_pk_bf16(float a, float b) {
  uint32_t r;
  asm("v_cvt_pk_bf16_f32 %0, %1, %2" : "=v"(r) : "v"(a), "v"(b));
  return r;
}

// raw 2^x (v_exp_f32 IS exp2)
__device__ __forceinline__ float exp2f_fast(float x) {
  float r;
  asm("v_exp_f32 %0, %1" : "=v"(r) : "v"(x));
  return r;
}

__device__ __forceinline__ void glds16(const ushort* g, ushort* l) {
  __builtin_amdgcn_global_load_lds(
      (const __attribute__((address_space(1))) void*)g,
      (__attribute__((address_space(3))) void*)l, 16, 0, 0);
}

#define MAX3(a, b, c) fmaxf(fmaxf((a), (b)), (c))

// ---------------- weight ingest: fp32 [1024][1024] -> bf16 transposed (4 fused) ----------------
__global__ __launch_bounds__(256) void transposeW4(
    const float* __restrict__ s0, const float* __restrict__ s1,
    const float* __restrict__ s2, const float* __restrict__ s3,
    ushort* __restrict__ dbase) {
  __shared__ __align__(16) ushort tile[64][72];
  const int t = threadIdx.x;
  const int bx = blockIdx.x & 15;   // src col block
  const int by = blockIdx.x >> 4;   // src row block
  const int wsel = blockIdx.y;
  const float* src = wsel == 0 ? s0 : (wsel == 1 ? s1 : (wsel == 2 ? s2 : s3));
  ushort* dst = dbase + (size_t)wsel * 1024 * 1024;
#pragma unroll
  for (int i = 0; i < 2; i++) {
    int e = (i * 256 + t) * 8;
    int r = e >> 6, c = e & 63;
    const float* sp = src + (size_t)(by * 64 + r) * 1024 + bx * 64 + c;
    float4 a = ((const float4*)sp)[0];
    float4 b = ((const float4*)sp)[1];
    tile[r][c + 0] = f2bf(a.x); tile[r][c + 1] = f2bf(a.y);
    tile[r][c + 2] = f2bf(a.z); tile[r][c + 3] = f2bf(a.w);
    tile[r][c + 4] = f2bf(b.x); tile[r][c + 5] = f2bf(b.y);
    tile[r][c + 6] = f2bf(b.z); tile[r][c + 7] = f2bf(b.w);
  }
  __syncthreads();
#pragma unroll
  for (int i = 0; i < 2; i++) {
    int e = (i * 256 + t) * 8;
    int r = e >> 6, c = e & 63;
    U8 st;
#pragma unroll
    for (int j = 0; j < 8; j++) st.u[j] = tile[c + j][r];
    *(short8*)(dst + (size_t)(bx * 64 + r) * 1024 + by * 64 + c) = st.v;
  }
}

// GEMM LDS tile swizzle (R8): phys_chunk = logical_chunk ^ ((row>>1)&3); read
// chunk (lane>>4) ^ ((lane>>1)&3). Conflicts verified 0 (R9). Neutral on time but
// kept (strictly correct + free).

// ---------------- fused QKV projection GEMM (z = 0/1/2 -> Q/K/V) ----------------
// FUSED is the bench-level winner (R7/R9 post-mortems; profiled ~120us is a
// cold-cache artifact — bench-level ~56us with L3-warm A inputs).
// z=0: Q -> bf16 head-split [B][H][S][64], oscale = log2(e)/8
// z=1: K -> bf16 head-split [B][H][S][64]
// z=2: V -> bf16 V^T [BH][64][S] with 8B-subchunk swizzle (phys = logical ^ (d&15))
__global__ __launch_bounds__(256, 2) void gemm_qkv(
    const float* __restrict__ Qa, const float* __restrict__ Ka, const float* __restrict__ Va,
    const ushort* __restrict__ WT,
    const float* __restrict__ bq, const float* __restrict__ bk, const float* __restrict__ bv,
    ushort* __restrict__ qws, ushort* __restrict__ kws, ushort* __restrict__ vt) {
  __shared__ __align__(16) ushort lA[128 * 32];
  __shared__ __align__(16) ushort lB[128 * 32];
  const int z = blockIdx.z;
  const float* Ap = z == 0 ? Qa : (z == 1 ? Ka : Va);
  const ushort* BT = WT + (size_t)z * 1024 * 1024;
  const float* bias = z == 0 ? bq : (z == 1 ? bk : bv);
  const float oscale = z == 0 ? 0.18033688f : 1.0f;  // (1/8)*log2(e) on Q
  const int t = threadIdx.x;
  const int lane = t & 63;
  const int w = t >> 6;
  const int wr = w >> 1, wc = w & 1;
  const int bm0 = blockIdx.x * 128;
  const int bn0 = blockIdx.y * 128;
  f32x4 acc[4][4] = {};

  const int arow = t >> 2;
  const int acol = (t & 3) * 8;                       // A fp32 source (unswizzled; reg-staged)
  const int swz  = ((t & 3) ^ ((t >> 3) & 3)) * 8;    // swizzled chunk (stage key)
  const int rdo  = (((lane >> 4) ^ ((lane >> 1) & 3))) * 8;  // read chunk offset
  const float* fA0 = Ap + (size_t)(bm0 + arow) * 1024 + acol;
  const float* fA1 = Ap + (size_t)(bm0 + 64 + arow) * 1024 + acol;
  const ushort* gB0 = BT + (size_t)(bn0 + arow) * 1024 + swz;       // pre-swizzled source col
  const ushort* gB1 = BT + (size_t)(bn0 + 64 + arow) * 1024 + swz;
  ushort* lAs0 = &lA[(t >> 2) * 32 + swz];            // swizzled ds_write dests
  ushort* lAs1 = &lA[2048 + (t >> 2) * 32 + swz];

  float4 px0 = ((const float4*)fA0)[0];
  float4 px1 = ((const float4*)fA0)[1];
  float4 py0 = ((const float4*)fA1)[0];
  float4 py1 = ((const float4*)fA1)[1];

  for (int k0 = 0; k0 < 1024; k0 += 32) {
    if (k0) __syncthreads();
    union { short8 v; uint32_t u[4]; } s0, s1;
    s0.u[0] = cvt_pk_bf16(px0.x, px0.y); s0.u[1] = cvt_pk_bf16(px0.z, px0.w);
    s0.u[2] = cvt_pk_bf16(px1.x, px1.y); s0.u[3] = cvt_pk_bf16(px1.z, px1.w);
    s1.u[0] = cvt_pk_bf16(py0.x, py0.y); s1.u[1] = cvt_pk_bf16(py0.z, py0.w);
    s1.u[2] = cvt_pk_bf16(py1.x, py1.y); s1.u[3] = cvt_pk_bf16(py1.z, py1.w);
    *(short8*)lAs0 = s0.v;
    *(short8*)lAs1 = s1.v;
    glds16(gB0 + k0, &lB[t * 8]);
    glds16(gB1 + k0, &lB[2048 + t * 8]);
    __syncthreads();
    // prefetch next A slab AFTER the barrier (excluded from vmcnt(0) drain)
    if (k0 + 32 < 1024) {
      px0 = ((const float4*)(fA0 + k0 + 32))[0];
      px1 = ((const float4*)(fA0 + k0 + 32))[1];
      py0 = ((const float4*)(fA1 + k0 + 32))[0];
      py1 = ((const float4*)(fA1 + k0 + 32))[1];
    }
    short8 af[4], bf[4];
#pragma unroll
    for (int i = 0; i < 4; i++)
      af[i] = *(const short8*)&lA[(wr * 64 + i * 16 + (lane & 15)) * 32 + rdo];
#pragma unroll
    for (int j = 0; j < 4; j++)
      bf[j] = *(const short8*)&lB[(wc * 64 + j * 16 + (lane & 15)) * 32 + rdo];
#pragma unroll
    for (int i = 0; i < 4; i++)
#pragma unroll
      for (int j = 0; j < 4; j++)
        acc[i][j] = __builtin_amdgcn_mfma_f32_16x16x32_bf16(af[i], bf[j], acc[i][j], 0, 0, 0);
  }

  const int r0 = (lane >> 4) * 4;
#pragma unroll
  for (int j = 0; j < 4; j++) {
    const int col = bn0 + wc * 64 + j * 16 + (lane & 15);
    const float bc = bias[col];
#pragma unroll
    for (int i = 0; i < 4; i++) {
      const int row = bm0 + wr * 64 + i * 16 + r0;   // row % 4 == 0
      const int bb = row >> 11, s = row & 2047;
      const int hh = col >> 6, d = col & 63;
      if (z == 2) {
        uint32_t p01 = cvt_pk_bf16(acc[i][j][0] + bc, acc[i][j][1] + bc);
        uint32_t p23 = cvt_pk_bf16(acc[i][j][2] + bc, acc[i][j][3] + bc);
        ushort* vtb = vt + (((size_t)bb * H_ + hh) * HD + d) * (size_t)S_;
        const int sc = (s & 63) >> 2;
        *(uint2*)(vtb + (s & ~63) + ((sc ^ (d & 15)) << 2)) = (uint2){p01, p23};
      } else {
        ushort* dst = z == 0 ? qws : kws;
#pragma unroll
        for (int r = 0; r < 4; r++) {
          float val = (acc[i][j][r] + bc) * oscale;
          dst[(((size_t)bb * H_ + hh) * S_ + (s + r)) * HD + d] = f2bf(val);
        }
      }
    }
  }
}

// ---------------- output projection GEMM: fp32 C = A_bf16 * BT^T + bias ----------------
__global__ __launch_bounds__(256, 2) void gemm_out(
    const ushort* __restrict__ Ap, const ushort* __restrict__ BT,
    const float* __restrict__ bias, float* __restrict__ Cp) {
  __shared__ __align__(16) ushort lA[128 * 32];
  __shared__ __align__(16) ushort lB[128 * 32];
  const int t = threadIdx.x;
  const int lane = t & 63;
  const int w = t >> 6;
  const int wr = w >> 1, wc = w & 1;
  const int bm0 = blockIdx.x * 128;
  const int bn0 = blockIdx.y * 128;
  f32x4 acc[4][4] = {};

  const int arow = t >> 2;
  const int swz  = ((t & 3) ^ ((t >> 3) & 3)) * 8;
  const int rdo  = (((lane >> 4) ^ ((lane >> 1) & 3))) * 8;
  const ushort* gA0 = Ap + (size_t)(bm0 + arow) * 1024 + swz;
  const ushort* gA1 = Ap + (size_t)(bm0 + 64 + arow) * 1024 + swz;
  const ushort* gB0 = BT + (size_t)(bn0 + arow) * 1024 + swz;
  const ushort* gB1 = BT + (size_t)(bn0 + 64 + arow) * 1024 + swz;

  for (int k0 = 0; k0 < 1024; k0 += 32) {
    if (k0) __syncthreads();
    glds16(gA0 + k0, &lA[t * 8]);
    glds16(gA1 + k0, &lA[2048 + t * 8]);
    glds16(gB0 + k0, &lB[t * 8]);
    glds16(gB1 + k0, &lB[2048 + t * 8]);
    __syncthreads();
    short8 af[4], bf[4];
#pragma unroll
    for (int i = 0; i < 4; i++)
      af[i] = *(const short8*)&lA[(wr * 64 + i * 16 + (lane & 15)) * 32 + rdo];
#pragma unroll
    for (int j = 0; j < 4; j++)
      bf[j] = *(const short8*)&lB[(wc * 64 + j * 16 + (lane & 15)) * 32 + rdo];
#pragma unroll
    for (int i = 0; i < 4; i++)
#pragma unroll
      for (int j = 0; j < 4; j++)
        acc[i][j] = __builtin_amdgcn_mfma_f32_16x16x32_bf16(af[i], bf[j], acc[i][j], 0, 0, 0);
  }

  const int r0 = (lane >> 4) * 4;
#pragma unroll
  for (int j = 0; j < 4; j++) {
    const int col = bn0 + wc * 64 + j * 16 + (lane & 15);
    const float bc = bias[col];
#pragma unroll
    for (int i = 0; i < 4; i++) {
      const int row = bm0 + wr * 64 + i * 16 + r0;
#pragma unroll
      for (int r = 0; r < 4; r++)
        Cp[(size_t)(row + r) * 1024 + col] = acc[i][j][r] + bc;
    }
  }
}

// ---------------- flash attention: KV-SPLIT wave pairs (R9 experiment) ----------------
// R9 post-mortem: attn pinned 101-113us across occupancy/KVBLK/barrier/setprio
// variants; both pipes <50%; issue-work arithmetic predicts a ~4x smaller wall ->
// stall is the SERIAL KV dependency chain (32 tile-steps chained through o/m/l),
// the one dimension never varied. THIS ROUND: 512-thread blocks; waves 0-3 walk
// kv [0,1024), waves 4-7 walk [1024,2048) for the same 256-row Q-tile (qi=4,
// KVBLK=64 each). Serial depth halves, waves/CU doubles (16), total LDS traffic
// unchanged. Partials merge exactly (online-softmax algebra) via a 2-pass LDS
// exchange (stride-37 floats = conflict-free); waves 0-3 store.
// LDS: 64KB tiles (2 kvh x dbuf x (8KB K + 8KB V)), reused as merge exchange.
__global__ __launch_bounds__(512, 4) void attn(
    const ushort* __restrict__ q, const ushort* __restrict__ k,
    const ushort* __restrict__ vt, ushort* __restrict__ o) {
  __shared__ __align__(16) ushort smem[32768];   // 64 KB
  const int t = threadIdx.x;
  const int lane = t & 63;
  const int w = t >> 6;          // 0..7
  const int wq = w & 3;          // q sub-tile (64 rows)
  const int kvh = w >> 2;        // kv half
  // XCD-bijective swizzle: 512 blocks, 8 q-tiles/head -> each XCD owns 8 whole heads
  const int L = ((blockIdx.x & 7) << 6) + (blockIdx.x >> 3);
  const int bh = L >> 3;
  const int q0 = (L & 7) * 256;
  const int b = bh >> 4, h = bh & 15;
  const int l15 = lane & 15;
  const int g = lane >> 4;

  const ushort* kbase  = k  + (size_t)bh * S_ * HD;
  const ushort* vtbase = vt + (size_t)bh * HD * S_;

  // Q fragments: 64 rows per wave (4 x 16), hd=64 in two x-slabs (MFMA B operand)
  short8 qf[4][2];
#pragma unroll
  for (int qi = 0; qi < 4; qi++) {
    const ushort* qp = q + ((size_t)bh * S_ + q0 + wq * 64 + qi * 16 + l15) * HD + g * 8;
    qf[qi][0] = *(const short8*)qp;
    qf[qi][1] = *(const short8*)(qp + 32);
  }

  // ones A-fragment for l accumulation (bf16 1.0 = 0x3F80)
  short8 onesf;
#pragma unroll
  for (int j = 0; j < 8; j++) onesf[j] = (short)0x3F80;

  float m_r[4] = {-1e30f, -1e30f, -1e30f, -1e30f};
  f32x4 l_acc[4];
  f32x4 o_acc[4][4];
#pragma unroll
  for (int qi = 0; qi < 4; qi++) {
    l_acc[qi] = (f32x4){0.f, 0.f, 0.f, 0.f};
#pragma unroll
    for (int cb = 0; cb < 4; cb++) o_acc[qi][cb] = (f32x4){0.f, 0.f, 0.f, 0.f};
  }

  // V-read sub-chunk offsets (ushort units), loop/cb-invariant: (8ks+g+{0,4}) ^ l15
  int vo[2][2];
#pragma unroll
  for (int ks = 0; ks < 2; ks++) {
    vo[ks][0] = ((8 * ks + g) ^ l15) << 2;
    vo[ks][1] = ((8 * ks + 4 + g) ^ l15) << 2;
  }

  // LDS layout (ushort idx): K tiles [kvh*8192 + sel*4096 + ...],
  //                          V tiles [16384 + kvh*8192 + sel*4096 + ...]
  // stage one 64-kv tile for this wave's kv-half; 256 threads (4 waves) per group
  auto STAGE = [&](int sel_, int kv0) {
    const int tt = t & 255;
#pragma unroll
    for (int i = 0; i < 2; i++) {
      int c = i * 256 + tt;            // 16B-chunk index, 512 chunks per tile
      int row = c >> 3;
      int cc = (c & 7) ^ (row & 7);    // pre-swizzled source chunk (K only)
      glds16(kbase + (size_t)(kv0 + row) * HD + cc * 8, &smem[kvh * 8192 + sel_ * 4096 + c * 8]);
      glds16(vtbase + (size_t)row * S_ + kv0 + (c & 7) * 8,
             &smem[16384 + kvh * 8192 + sel_ * 4096 + c * 8]);
    }
  };

  const int kvstart = kvh * 1024;
  STAGE(0, kvstart);
  __syncthreads();

  int sel = 0;
  for (int r = 0; r < 16; r++, sel ^= 1) {
    const int kv0 = kvstart + r * 64;
    if (r + 1 < 16) STAGE(sel ^ 1, kv0 + 64);
    const ushort* kb  = &smem[kvh * 8192 + sel * 4096];
    const ushort* vbb = &smem[16384 + kvh * 8192 + sel * 4096];

    // ---- S^T = K (Q*log2e/8)^T : lane holds k-rows (4g+r per cb) of q-col l15 ----
    f32x4 sc[4][4];
#pragma unroll
    for (int qi = 0; qi < 4; qi++)
#pragma unroll
      for (int cb = 0; cb < 4; cb++) sc[qi][cb] = (f32x4){0.f, 0.f, 0.f, 0.f};
#pragma unroll
    for (int cb = 0; cb < 4; cb++) {
      const int row = cb * 16 + l15;
      const int r7 = row & 7;
      short8 kf0 = *(const short8*)&kb[(row * 8 + (g ^ r7)) * 8];
      short8 kf1 = *(const short8*)&kb[(row * 8 + ((4 + g) ^ r7)) * 8];
#pragma unroll
      for (int qi = 0; qi < 4; qi++) {
        sc[qi][cb] = __builtin_amdgcn_mfma_f32_16x16x32_bf16(kf0, qf[qi][0], sc[qi][cb], 0, 0, 0);
        sc[qi][cb] = __builtin_amdgcn_mfma_f32_16x16x32_bf16(kf1, qf[qi][1], sc[qi][cb], 0, 0, 0);
      }
    }

    // ---- softmax per qi (optimistic exp; shfl max off critical path) ----
    union PB { short8 v; uint32_t u[4]; } pbq[4][2];
#pragma unroll
    for (int qi = 0; qi < 4; qi++) {
      const float m = m_r[qi];
#pragma unroll
      for (int cb = 0; cb < 4; cb++) {
        float p0 = exp2f_fast(sc[qi][cb][0] - m);
        float p1 = exp2f_fast(sc[qi][cb][1] - m);
        float p2 = exp2f_fast(sc[qi][cb][2] - m);
        float p3 = exp2f_fast(sc[qi][cb][3] - m);
        pbq[qi][cb >> 1].u[(cb & 1) * 2 + 0] = cvt_pk_bf16(p0, p1);
        pbq[qi][cb >> 1].u[(cb & 1) * 2 + 1] = cvt_pk_bf16(p2, p3);
      }
      float z0 = MAX3(sc[qi][0][0], sc[qi][0][1], sc[qi][0][2]);
      float z1 = MAX3(sc[qi][0][3], sc[qi][1][0], sc[qi][1][1]);
      float z2 = MAX3(sc[qi][1][2], sc[qi][1][3], sc[qi][2][0]);
      float z3 = MAX3(sc[qi][2][1], sc[qi][2][2], sc[qi][2][3]);
      float z4 = MAX3(sc[qi][3][0], sc[qi][3][1], sc[qi][3][2]);
      float mx = MAX3(MAX3(z0, z1, z2), fmaxf(z3, z4), sc[qi][3][3]);
      mx = fmaxf(mx, __shfl_xor(mx, 16));
      mx = fmaxf(mx, __shfl_xor(mx, 32));

      const float THR = 11.5415603f;  // 8 * log2(e)
      if (!__all(mx <= m + THR)) {
        float mn = fmaxf(m, mx);
        float fct = exp2f_fast(m - mn);
        m_r[qi] = mn;
        l_acc[qi] *= fct;
#pragma unroll
        for (int cb = 0; cb < 4; cb++)
#pragma unroll
          for (int rr = 0; rr < 4; rr++) o_acc[qi][cb][rr] *= fct;
#pragma unroll
        for (int cb = 0; cb < 4; cb++) {
          float p0 = exp2f_fast(sc[qi][cb][0] - mn);
          float p1 = exp2f_fast(sc[qi][cb][1] - mn);
          float p2 = exp2f_fast(sc[qi][cb][2] - mn);
          float p3 = exp2f_fast(sc[qi][cb][3] - mn);
          pbq[qi][cb >> 1].u[(cb & 1) * 2 + 0] = cvt_pk_bf16(p0, p1);
          pbq[qi][cb >> 1].u[(cb & 1) * 2 + 1] = cvt_pk_bf16(p2, p3);
        }
      }
    }

    // ---- O^T += V^T P^T, l += 1.P ; vv loaded once per (ks,cb), reused by 4 qi ----
#pragma unroll
    for (int ks = 0; ks < 2; ks++) {
#pragma unroll
      for (int qi = 0; qi < 4; qi++)
        l_acc[qi] = __builtin_amdgcn_mfma_f32_16x16x32_bf16(onesf, pbq[qi][ks].v, l_acc[qi], 0, 0, 0);
#pragma unroll
      for (int cb = 0; cb < 4; cb++) {
        const ushort* vb = &vbb[(cb * 16 + l15) * 64];
        union { short8 v; uint2 d2[2]; } vv;
        vv.d2[0] = *(const uint2*)(vb + vo[ks][0]);
        vv.d2[1] = *(const uint2*)(vb + vo[ks][1]);
#pragma unroll
        for (int qi = 0; qi < 4; qi++)
          o_acc[qi][cb] = __builtin_amdgcn_mfma_f32_16x16x32_bf16(vv.v, pbq[qi][ks].v, o_acc[qi][cb], 0, 0, 0);
      }
    }
    __syncthreads();
  }

  // ---- merge the two kv-half partials (exact online-softmax combine) ----
  // 2 passes of 2 qi each; stride-37 float slots (37 mod 32 = 5, coprime -> no bank conflicts)
  float* xf = (float*)smem;
#pragma unroll
  for (int p = 0; p < 2; p++) {
    if (w >= 4) {
      const int slot = ((w - 4) * 64 + lane) * 37;
#pragma unroll
      for (int qq = 0; qq < 2; qq++) {
        const int qi = p * 2 + qq;
#pragma unroll
        for (int cb = 0; cb < 4; cb++)
#pragma unroll
          for (int rr = 0; rr < 4; rr++)
            xf[slot + qq * 16 + cb * 4 + rr] = o_acc[qi][cb][rr];
        xf[slot + 32 + qq] = l_acc[qi][0];
        xf[slot + 34 + qq] = m_r[qi];
      }
    }
    __syncthreads();
    if (w < 4) {
      const int slot = (w * 64 + lane) * 37;
#pragma unroll
      for (int qq = 0; qq < 2; qq++) {
        const int qi = p * 2 + qq;
        const float mb = xf[slot + 34 + qq];
        const float lb = xf[slot + 32 + qq];
        const float mn = fmaxf(m_r[qi], mb);
        const float fa = exp2f_fast(m_r[qi] - mn);
        const float fb = exp2f_fast(mb - mn);
        m_r[qi] = mn;
        l_acc[qi][0] = l_acc[qi][0] * fa + lb * fb;
#pragma unroll
        for (int cb = 0; cb < 4; cb++)
#pragma unroll
          for (int rr = 0; rr < 4; rr++)
            o_acc[qi][cb][rr] = o_acc[qi][cb][rr] * fa + xf[slot + qq * 16 + cb * 4 + rr] * fb;
      }
    }
    __syncthreads();
  }

  // ---- epilogue: O^T / l -> o[B][S][H*64] (bf16, packed 8B stores); waves 0-3 only ----
  if (w < 4) {
#pragma unroll
    for (int qi = 0; qi < 4; qi++) {
      const float inv = 1.f / l_acc[qi][0];
      ushort* ob = o + ((size_t)b * S_ + q0 + wq * 64 + qi * 16 + l15) * DM + h * HD + 4 * g;
#pragma unroll
      for (int cb = 0; cb < 4; cb++) {
        uint2 st;
        st.x = cvt_pk_bf16(o_acc[qi][cb][0] * inv, o_acc[qi][cb][1] * inv);
        st.y = cvt_pk_bf16(o_acc[qi][cb][2] * inv, o_acc[qi][cb][3] * inv);
        *(uint2*)(ob + cb * 16) = st;
      }
    }
  }
}

// ---------------- launch ----------------
extern "C" void kernel_launch(void* const* d_in, const int* in_sizes, int n_in,
                              void* d_out, int out_size, void* d_ws, size_t ws_size,
                              hipStream_t stream) {
  const float* Q  = (const float*)d_in[0];
  const float* K  = (const float*)d_in[1];
  const float* V  = (const float*)d_in[2];
  const float* Wq = (const float*)d_in[3];
  const float* bq = (const float*)d_in[4];
  const float* Wk = (const float*)d_in[5];
  const float* bk = (const float*)d_in[6];
  const float* Wv = (const float*)d_in[7];
  const float* bv = (const float*)d_in[8];
  const float* Wo = (const float*)d_in[9];
  const float* bo = (const float*)d_in[10];
  float* out = (float*)d_out;
  ushort* ws = (ushort*)d_ws;

  const size_t WN = (size_t)1024 * 1024;       // weight elems
  const size_t PN = (size_t)B_ * S_ * DM;      // activation elems (8.39M)
  ushort* wT  = ws;                             // wq/wk/wv/wo transposed, contiguous
  ushort* woT = ws + 3 * WN;
  ushort* qws = ws + 4 * WN;
  ushort* kws = qws + PN;
  ushort* ows = kws + PN;
  ushort* vt  = (ushort*)d_out;  // V^T scratch in d_out (bf16 16.8MB < fp32 33.5MB); overwritten by final GEMM

  transposeW4<<<dim3(256, 4), 256, 0, stream>>>(Wq, Wk, Wv, Wo, wT);

  // fused Q/K/V projections (bench-level winner per R7/R9 post-mortems)
  gemm_qkv<<<dim3(64, 8, 3), 256, 0, stream>>>(Q, K, V, wT, bq, bk, bv, qws, kws, vt);

  attn<<<BH * 8, 512, 0, stream>>>(qws, kws, vt, ows);

  gemm_out<<<dim3(64, 8), 256, 0, stream>>>(ows, woT, bo, out);
}

// Round 11
// 191.985 us; speedup vs baseline: 3.0954x; 3.0954x over previous
//
#include <hip/hip_runtime.h>
#include <hip/hip_bf16.h>
#include <stdint.h>

// MHA: B=4, S=2048, D_MODEL=1024, H=16, hd=64.
// Interface: fp32 in / fp32 out. Internal compute: bf16 MFMA.

#define B_  4
#define S_  2048
#define DM  1024
#define H_  16
#define HD  64
#define BH  (B_ * H_)

typedef __attribute__((ext_vector_type(8))) short short8;
typedef __attribute__((ext_vector_type(4))) float f32x4;

union U8 { short8 v; ushort u[8]; };

__device__ __forceinline__ ushort f2bf(float f) {
  union { float f; uint32_t i; } x; x.f = f;
  uint32_t r = (x.i + 0x7FFFu + ((x.i >> 16) & 1u)) >> 16;
  return (ushort)r;
}

// packed f32x2 -> bf16x2 (RNE), gfx950 hw convert; no builtin exists (m240)
__device__ __forceinline__ uint32_t cvt_pk_bf16(float a, float b) {
  uint32_t r;
  asm("v_cvt_pk_bf16_f32 %0, %1, %2" : "=v"(r) : "v"(a), "v"(b));
  return r;
}

// raw 2^x (v_exp_f32 IS exp2)
__device__ __forceinline__ float exp2f_fast(float x) {
  float r;
  asm("v_exp_f32 %0, %1" : "=v"(r) : "v"(x));
  return r;
}

__device__ __forceinline__ void glds16(const ushort* g, ushort* l) {
  __builtin_amdgcn_global_load_lds(
      (const __attribute__((address_space(1))) void*)g,
      (__attribute__((address_space(3))) void*)l, 16, 0, 0);
}

#define MAX3(a, b, c) fmaxf(fmaxf((a), (b)), (c))

// ---------------- weight ingest: fp32 [1024][1024] -> bf16 transposed (4 fused) ----------------
__global__ __launch_bounds__(256) void transposeW4(
    const float* __restrict__ s0, const float* __restrict__ s1,
    const float* __restrict__ s2, const float* __restrict__ s3,
    ushort* __restrict__ dbase) {
  __shared__ __align__(16) ushort tile[64][72];
  const int t = threadIdx.x;
  const int bx = blockIdx.x & 15;   // src col block
  const int by = blockIdx.x >> 4;   // src row block
  const int wsel = blockIdx.y;
  const float* src = wsel == 0 ? s0 : (wsel == 1 ? s1 : (wsel == 2 ? s2 : s3));
  ushort* dst = dbase + (size_t)wsel * 1024 * 1024;
#pragma unroll
  for (int i = 0; i < 2; i++) {
    int e = (i * 256 + t) * 8;
    int r = e >> 6, c = e & 63;
    const float* sp = src + (size_t)(by * 64 + r) * 1024 + bx * 64 + c;
    float4 a = ((const float4*)sp)[0];
    float4 b = ((const float4*)sp)[1];
    tile[r][c + 0] = f2bf(a.x); tile[r][c + 1] = f2bf(a.y);
    tile[r][c + 2] = f2bf(a.z); tile[r][c + 3] = f2bf(a.w);
    tile[r][c + 4] = f2bf(b.x); tile[r][c + 5] = f2bf(b.y);
    tile[r][c + 6] = f2bf(b.z); tile[r][c + 7] = f2bf(b.w);
  }
  __syncthreads();
#pragma unroll
  for (int i = 0; i < 2; i++) {
    int e = (i * 256 + t) * 8;
    int r = e >> 6, c = e & 63;
    U8 st;
#pragma unroll
    for (int j = 0; j < 8; j++) st.u[j] = tile[c + j][r];
    *(short8*)(dst + (size_t)(bx * 64 + r) * 1024 + by * 64 + c) = st.v;
  }
}

// GEMM LDS tile swizzle (R8): phys_chunk = logical_chunk ^ ((row>>1)&3); read
// chunk (lane>>4) ^ ((lane>>1)&3). Conflicts verified 0 (R9).

// ---------------- fused QKV projection GEMM (z = 0/1/2 -> Q/K/V) ----------------
// FUSED is the bench-level winner (R7/R9 post-mortems; profiled ~120us is a
// cold-cache artifact — bench-level ~56us with L3-warm A inputs).
// z=0: Q -> bf16 head-split [B][H][S][64], oscale = log2(e)/8
// z=1: K -> bf16 head-split [B][H][S][64]
// z=2: V -> bf16 V^T [BH][64][S] with 8B-subchunk swizzle (phys = logical ^ (d&15))
__global__ __launch_bounds__(256, 2) void gemm_qkv(
    const float* __restrict__ Qa, const float* __restrict__ Ka, const float* __restrict__ Va,
    const ushort* __restrict__ WT,
    const float* __restrict__ bq, const float* __restrict__ bk, const float* __restrict__ bv,
    ushort* __restrict__ qws, ushort* __restrict__ kws, ushort* __restrict__ vt) {
  __shared__ __align__(16) ushort lA[128 * 32];
  __shared__ __align__(16) ushort lB[128 * 32];
  const int z = blockIdx.z;
  const float* Ap = z == 0 ? Qa : (z == 1 ? Ka : Va);
  const ushort* BT = WT + (size_t)z * 1024 * 1024;
  const float* bias = z == 0 ? bq : (z == 1 ? bk : bv);
  const float oscale = z == 0 ? 0.18033688f : 1.0f;  // (1/8)*log2(e) on Q
  const int t = threadIdx.x;
  const int lane = t & 63;
  const int w = t >> 6;
  const int wr = w >> 1, wc = w & 1;
  const int bm0 = blockIdx.x * 128;
  const int bn0 = blockIdx.y * 128;
  f32x4 acc[4][4] = {};

  const int arow = t >> 2;
  const int acol = (t & 3) * 8;                       // A fp32 source (unswizzled; reg-staged)
  const int swz  = ((t & 3) ^ ((t >> 3) & 3)) * 8;    // swizzled chunk (stage key)
  const int rdo  = (((lane >> 4) ^ ((lane >> 1) & 3))) * 8;  // read chunk offset
  const float* fA0 = Ap + (size_t)(bm0 + arow) * 1024 + acol;
  const float* fA1 = Ap + (size_t)(bm0 + 64 + arow) * 1024 + acol;
  const ushort* gB0 = BT + (size_t)(bn0 + arow) * 1024 + swz;       // pre-swizzled source col
  const ushort* gB1 = BT + (size_t)(bn0 + 64 + arow) * 1024 + swz;
  ushort* lAs0 = &lA[(t >> 2) * 32 + swz];            // swizzled ds_write dests
  ushort* lAs1 = &lA[2048 + (t >> 2) * 32 + swz];

  float4 px0 = ((const float4*)fA0)[0];
  float4 px1 = ((const float4*)fA0)[1];
  float4 py0 = ((const float4*)fA1)[0];
  float4 py1 = ((const float4*)fA1)[1];

  for (int k0 = 0; k0 < 1024; k0 += 32) {
    if (k0) __syncthreads();
    union { short8 v; uint32_t u[4]; } s0, s1;
    s0.u[0] = cvt_pk_bf16(px0.x, px0.y); s0.u[1] = cvt_pk_bf16(px0.z, px0.w);
    s0.u[2] = cvt_pk_bf16(px1.x, px1.y); s0.u[3] = cvt_pk_bf16(px1.z, px1.w);
    s1.u[0] = cvt_pk_bf16(py0.x, py0.y); s1.u[1] = cvt_pk_bf16(py0.z, py0.w);
    s1.u[2] = cvt_pk_bf16(py1.x, py1.y); s1.u[3] = cvt_pk_bf16(py1.z, py1.w);
    *(short8*)lAs0 = s0.v;
    *(short8*)lAs1 = s1.v;
    glds16(gB0 + k0, &lB[t * 8]);
    glds16(gB1 + k0, &lB[2048 + t * 8]);
    __syncthreads();
    // prefetch next A slab AFTER the barrier (excluded from vmcnt(0) drain)
    if (k0 + 32 < 1024) {
      px0 = ((const float4*)(fA0 + k0 + 32))[0];
      px1 = ((const float4*)(fA0 + k0 + 32))[1];
      py0 = ((const float4*)(fA1 + k0 + 32))[0];
      py1 = ((const float4*)(fA1 + k0 + 32))[1];
    }
    short8 af[4], bf[4];
#pragma unroll
    for (int i = 0; i < 4; i++)
      af[i] = *(const short8*)&lA[(wr * 64 + i * 16 + (lane & 15)) * 32 + rdo];
#pragma unroll
    for (int j = 0; j < 4; j++)
      bf[j] = *(const short8*)&lB[(wc * 64 + j * 16 + (lane & 15)) * 32 + rdo];
#pragma unroll
    for (int i = 0; i < 4; i++)
#pragma unroll
      for (int j = 0; j < 4; j++)
        acc[i][j] = __builtin_amdgcn_mfma_f32_16x16x32_bf16(af[i], bf[j], acc[i][j], 0, 0, 0);
  }

  const int r0 = (lane >> 4) * 4;
#pragma unroll
  for (int j = 0; j < 4; j++) {
    const int col = bn0 + wc * 64 + j * 16 + (lane & 15);
    const float bc = bias[col];
#pragma unroll
    for (int i = 0; i < 4; i++) {
      const int row = bm0 + wr * 64 + i * 16 + r0;   // row % 4 == 0
      const int bb = row >> 11, s = row & 2047;
      const int hh = col >> 6, d = col & 63;
      if (z == 2) {
        uint32_t p01 = cvt_pk_bf16(acc[i][j][0] + bc, acc[i][j][1] + bc);
        uint32_t p23 = cvt_pk_bf16(acc[i][j][2] + bc, acc[i][j][3] + bc);
        ushort* vtb = vt + (((size_t)bb * H_ + hh) * HD + d) * (size_t)S_;
        const int sc = (s & 63) >> 2;
        *(uint2*)(vtb + (s & ~63) + ((sc ^ (d & 15)) << 2)) = (uint2){p01, p23};
      } else {
        ushort* dst = z == 0 ? qws : kws;
#pragma unroll
        for (int r = 0; r < 4; r++) {
          float val = (acc[i][j][r] + bc) * oscale;
          dst[(((size_t)bb * H_ + hh) * S_ + (s + r)) * HD + d] = f2bf(val);
        }
      }
    }
  }
}

// ---------------- output projection GEMM: fp32 C = A_bf16 * BT^T + bias ----------------
__global__ __launch_bounds__(256, 2) void gemm_out(
    const ushort* __restrict__ Ap, const ushort* __restrict__ BT,
    const float* __restrict__ bias, float* __restrict__ Cp) {
  __shared__ __align__(16) ushort lA[128 * 32];
  __shared__ __align__(16) ushort lB[128 * 32];
  const int t = threadIdx.x;
  const int lane = t & 63;
  const int w = t >> 6;
  const int wr = w >> 1, wc = w & 1;
  const int bm0 = blockIdx.x * 128;
  const int bn0 = blockIdx.y * 128;
  f32x4 acc[4][4] = {};

  const int arow = t >> 2;
  const int swz  = ((t & 3) ^ ((t >> 3) & 3)) * 8;
  const int rdo  = (((lane >> 4) ^ ((lane >> 1) & 3))) * 8;
  const ushort* gA0 = Ap + (size_t)(bm0 + arow) * 1024 + swz;
  const ushort* gA1 = Ap + (size_t)(bm0 + 64 + arow) * 1024 + swz;
  const ushort* gB0 = BT + (size_t)(bn0 + arow) * 1024 + swz;
  const ushort* gB1 = BT + (size_t)(bn0 + 64 + arow) * 1024 + swz;

  for (int k0 = 0; k0 < 1024; k0 += 32) {
    if (k0) __syncthreads();
    glds16(gA0 + k0, &lA[t * 8]);
    glds16(gA1 + k0, &lA[2048 + t * 8]);
    glds16(gB0 + k0, &lB[t * 8]);
    glds16(gB1 + k0, &lB[2048 + t * 8]);
    __syncthreads();
    short8 af[4], bf[4];
#pragma unroll
    for (int i = 0; i < 4; i++)
      af[i] = *(const short8*)&lA[(wr * 64 + i * 16 + (lane & 15)) * 32 + rdo];
#pragma unroll
    for (int j = 0; j < 4; j++)
      bf[j] = *(const short8*)&lB[(wc * 64 + j * 16 + (lane & 15)) * 32 + rdo];
#pragma unroll
    for (int i = 0; i < 4; i++)
#pragma unroll
      for (int j = 0; j < 4; j++)
        acc[i][j] = __builtin_amdgcn_mfma_f32_16x16x32_bf16(af[i], bf[j], acc[i][j], 0, 0, 0);
  }

  const int r0 = (lane >> 4) * 4;
#pragma unroll
  for (int j = 0; j < 4; j++) {
    const int col = bn0 + wc * 64 + j * 16 + (lane & 15);
    const float bc = bias[col];
#pragma unroll
    for (int i = 0; i < 4; i++) {
      const int row = bm0 + wr * 64 + i * 16 + r0;
#pragma unroll
      for (int r = 0; r < 4; r++)
        Cp[(size_t)(row + r) * 1024 + col] = acc[i][j][r] + bc;
    }
  }
}

// ---------------- flash attention: KV-SPLIT wave pairs (R10 retry, spill fixed) ----------------
// R10 post-mortem: __launch_bounds__(512,4) was applied as 4 BLOCKS/CU (32 waves)
// -> 64-VGPR cap -> massive scratch spill (hbm_bytes 2.1GB, VGPR_Count=64); the
// KV-split experiment never actually ran. THIS ROUND: (512,2) -> cap >= 128 under
// either semantics; ~120 VGPR kernel fits; grid is 2 blocks/CU anyway (64KB LDS).
// Structure: waves 0-3 walk kv [0,1024), waves 4-7 walk [1024,2048) for the same
// 256-row Q-tile (qi=4, KVBLK=64 each). Serial depth halves, 16 waves/CU. Partials
// merge exactly (online-softmax algebra; verified correct in R10) via stride-37
// LDS exchange; waves 0-3 store.
__global__ __launch_bounds__(512, 2) void attn(
    const ushort* __restrict__ q, const ushort* __restrict__ k,
    const ushort* __restrict__ vt, ushort* __restrict__ o) {
  __shared__ __align__(16) ushort smem[32768];   // 64 KB
  const int t = threadIdx.x;
  const int lane = t & 63;
  const int w = t >> 6;          // 0..7
  const int wq = w & 3;          // q sub-tile (64 rows)
  const int kvh = w >> 2;        // kv half
  // XCD-bijective swizzle: 512 blocks, 8 q-tiles/head -> each XCD owns 8 whole heads
  const int L = ((blockIdx.x & 7) << 6) + (blockIdx.x >> 3);
  const int bh = L >> 3;
  const int q0 = (L & 7) * 256;
  const int b = bh >> 4, h = bh & 15;
  const int l15 = lane & 15;
  const int g = lane >> 4;

  const ushort* kbase  = k  + (size_t)bh * S_ * HD;
  const ushort* vtbase = vt + (size_t)bh * HD * S_;

  // Q fragments: 64 rows per wave (4 x 16), hd=64 in two x-slabs (MFMA B operand)
  short8 qf[4][2];
#pragma unroll
  for (int qi = 0; qi < 4; qi++) {
    const ushort* qp = q + ((size_t)bh * S_ + q0 + wq * 64 + qi * 16 + l15) * HD + g * 8;
    qf[qi][0] = *(const short8*)qp;
    qf[qi][1] = *(const short8*)(qp + 32);
  }

  // ones A-fragment for l accumulation (bf16 1.0 = 0x3F80)
  short8 onesf;
#pragma unroll
  for (int j = 0; j < 8; j++) onesf[j] = (short)0x3F80;

  float m_r[4] = {-1e30f, -1e30f, -1e30f, -1e30f};
  f32x4 l_acc[4];
  f32x4 o_acc[4][4];
#pragma unroll
  for (int qi = 0; qi < 4; qi++) {
    l_acc[qi] = (f32x4){0.f, 0.f, 0.f, 0.f};
#pragma unroll
    for (int cb = 0; cb < 4; cb++) o_acc[qi][cb] = (f32x4){0.f, 0.f, 0.f, 0.f};
  }

  // V-read sub-chunk offsets (ushort units), loop/cb-invariant: (8ks+g+{0,4}) ^ l15
  int vo[2][2];
#pragma unroll
  for (int ks = 0; ks < 2; ks++) {
    vo[ks][0] = ((8 * ks + g) ^ l15) << 2;
    vo[ks][1] = ((8 * ks + 4 + g) ^ l15) << 2;
  }

  // LDS layout (ushort idx): K tiles [kvh*8192 + sel*4096 + ...],
  //                          V tiles [16384 + kvh*8192 + sel*4096 + ...]
  // stage one 64-kv tile for this wave's kv-half; 256 threads (4 waves) per group
  auto STAGE = [&](int sel_, int kv0) {
    const int tt = t & 255;
#pragma unroll
    for (int i = 0; i < 2; i++) {
      int c = i * 256 + tt;            // 16B-chunk index, 512 chunks per tile
      int row = c >> 3;
      int cc = (c & 7) ^ (row & 7);    // pre-swizzled source chunk (K only)
      glds16(kbase + (size_t)(kv0 + row) * HD + cc * 8, &smem[kvh * 8192 + sel_ * 4096 + c * 8]);
      glds16(vtbase + (size_t)row * S_ + kv0 + (c & 7) * 8,
             &smem[16384 + kvh * 8192 + sel_ * 4096 + c * 8]);
    }
  };

  const int kvstart = kvh * 1024;
  STAGE(0, kvstart);
  __syncthreads();

  int sel = 0;
  for (int r = 0; r < 16; r++, sel ^= 1) {
    const int kv0 = kvstart + r * 64;
    if (r + 1 < 16) STAGE(sel ^ 1, kv0 + 64);
    const ushort* kb  = &smem[kvh * 8192 + sel * 4096];
    const ushort* vbb = &smem[16384 + kvh * 8192 + sel * 4096];

    // ---- S^T = K (Q*log2e/8)^T : lane holds k-rows (4g+r per cb) of q-col l15 ----
    f32x4 sc[4][4];
#pragma unroll
    for (int qi = 0; qi < 4; qi++)
#pragma unroll
      for (int cb = 0; cb < 4; cb++) sc[qi][cb] = (f32x4){0.f, 0.f, 0.f, 0.f};
#pragma unroll
    for (int cb = 0; cb < 4; cb++) {
      const int row = cb * 16 + l15;
      const int r7 = row & 7;
      short8 kf0 = *(const short8*)&kb[(row * 8 + (g ^ r7)) * 8];
      short8 kf1 = *(const short8*)&kb[(row * 8 + ((4 + g) ^ r7)) * 8];
#pragma unroll
      for (int qi = 0; qi < 4; qi++) {
        sc[qi][cb] = __builtin_amdgcn_mfma_f32_16x16x32_bf16(kf0, qf[qi][0], sc[qi][cb], 0, 0, 0);
        sc[qi][cb] = __builtin_amdgcn_mfma_f32_16x16x32_bf16(kf1, qf[qi][1], sc[qi][cb], 0, 0, 0);
      }
    }

    // ---- softmax per qi (optimistic exp; shfl max off critical path) ----
    union PB { short8 v; uint32_t u[4]; } pbq[4][2];
#pragma unroll
    for (int qi = 0; qi < 4; qi++) {
      const float m = m_r[qi];
#pragma unroll
      for (int cb = 0; cb < 4; cb++) {
        float p0 = exp2f_fast(sc[qi][cb][0] - m);
        float p1 = exp2f_fast(sc[qi][cb][1] - m);
        float p2 = exp2f_fast(sc[qi][cb][2] - m);
        float p3 = exp2f_fast(sc[qi][cb][3] - m);
        pbq[qi][cb >> 1].u[(cb & 1) * 2 + 0] = cvt_pk_bf16(p0, p1);
        pbq[qi][cb >> 1].u[(cb & 1) * 2 + 1] = cvt_pk_bf16(p2, p3);
      }
      float z0 = MAX3(sc[qi][0][0], sc[qi][0][1], sc[qi][0][2]);
      float z1 = MAX3(sc[qi][0][3], sc[qi][1][0], sc[qi][1][1]);
      float z2 = MAX3(sc[qi][1][2], sc[qi][1][3], sc[qi][2][0]);
      float z3 = MAX3(sc[qi][2][1], sc[qi][2][2], sc[qi][2][3]);
      float z4 = MAX3(sc[qi][3][0], sc[qi][3][1], sc[qi][3][2]);
      float mx = MAX3(MAX3(z0, z1, z2), fmaxf(z3, z4), sc[qi][3][3]);
      mx = fmaxf(mx, __shfl_xor(mx, 16));
      mx = fmaxf(mx, __shfl_xor(mx, 32));

      const float THR = 11.5415603f;  // 8 * log2(e)
      if (!__all(mx <= m + THR)) {
        float mn = fmaxf(m, mx);
        float fct = exp2f_fast(m - mn);
        m_r[qi] = mn;
        l_acc[qi] *= fct;
#pragma unroll
        for (int cb = 0; cb < 4; cb++)
#pragma unroll
          for (int rr = 0; rr < 4; rr++) o_acc[qi][cb][rr] *= fct;
#pragma unroll
        for (int cb = 0; cb < 4; cb++) {
          float p0 = exp2f_fast(sc[qi][cb][0] - mn);
          float p1 = exp2f_fast(sc[qi][cb][1] - mn);
          float p2 = exp2f_fast(sc[qi][cb][2] - mn);
          float p3 = exp2f_fast(sc[qi][cb][3] - mn);
          pbq[qi][cb >> 1].u[(cb & 1) * 2 + 0] = cvt_pk_bf16(p0, p1);
          pbq[qi][cb >> 1].u[(cb & 1) * 2 + 1] = cvt_pk_bf16(p2, p3);
        }
      }
    }

    // ---- O^T += V^T P^T, l += 1.P ; vv loaded once per (ks,cb), reused by 4 qi ----
#pragma unroll
    for (int ks = 0; ks < 2; ks++) {
#pragma unroll
      for (int qi = 0; qi < 4; qi++)
        l_acc[qi] = __builtin_amdgcn_mfma_f32_16x16x32_bf16(onesf, pbq[qi][ks].v, l_acc[qi], 0, 0, 0);
#pragma unroll
      for (int cb = 0; cb < 4; cb++) {
        const ushort* vb = &vbb[(cb * 16 + l15) * 64];
        union { short8 v; uint2 d2[2]; } vv;
        vv.d2[0] = *(const uint2*)(vb + vo[ks][0]);
        vv.d2[1] = *(const uint2*)(vb + vo[ks][1]);
#pragma unroll
        for (int qi = 0; qi < 4; qi++)
          o_acc[qi][cb] = __builtin_amdgcn_mfma_f32_16x16x32_bf16(vv.v, pbq[qi][ks].v, o_acc[qi][cb], 0, 0, 0);
      }
    }
    __syncthreads();
  }

  // ---- merge the two kv-half partials (exact online-softmax combine) ----
  // 2 passes of 2 qi each; stride-37 float slots (37 mod 32 = 5, coprime -> no bank conflicts)
  float* xf = (float*)smem;
#pragma unroll
  for (int p = 0; p < 2; p++) {
    if (w >= 4) {
      const int slot = ((w - 4) * 64 + lane) * 37;
#pragma unroll
      for (int qq = 0; qq < 2; qq++) {
        const int qi = p * 2 + qq;
#pragma unroll
        for (int cb = 0; cb < 4; cb++)
#pragma unroll
          for (int rr = 0; rr < 4; rr++)
            xf[slot + qq * 16 + cb * 4 + rr] = o_acc[qi][cb][rr];
        xf[slot + 32 + qq] = l_acc[qi][0];
        xf[slot + 34 + qq] = m_r[qi];
      }
    }
    __syncthreads();
    if (w < 4) {
      const int slot = (w * 64 + lane) * 37;
#pragma unroll
      for (int qq = 0; qq < 2; qq++) {
        const int qi = p * 2 + qq;
        const float mb = xf[slot + 34 + qq];
        const float lb = xf[slot + 32 + qq];
        const float mn = fmaxf(m_r[qi], mb);
        const float fa = exp2f_fast(m_r[qi] - mn);
        const float fb = exp2f_fast(mb - mn);
        m_r[qi] = mn;
        l_acc[qi][0] = l_acc[qi][0] * fa + lb * fb;
#pragma unroll
        for (int cb = 0; cb < 4; cb++)
#pragma unroll
          for (int rr = 0; rr < 4; rr++)
            o_acc[qi][cb][rr] = o_acc[qi][cb][rr] * fa + xf[slot + qq * 16 + cb * 4 + rr] * fb;
      }
    }
    __syncthreads();
  }

  // ---- epilogue: O^T / l -> o[B][S][H*64] (bf16, packed 8B stores); waves 0-3 only ----
  if (w < 4) {
#pragma unroll
    for (int qi = 0; qi < 4; qi++) {
      const float inv = 1.f / l_acc[qi][0];
      ushort* ob = o + ((size_t)b * S_ + q0 + wq * 64 + qi * 16 + l15) * DM + h * HD + 4 * g;
#pragma unroll
      for (int cb = 0; cb < 4; cb++) {
        uint2 st;
        st.x = cvt_pk_bf16(o_acc[qi][cb][0] * inv, o_acc[qi][cb][1] * inv);
        st.y = cvt_pk_bf16(o_acc[qi][cb][2] * inv, o_acc[qi][cb][3] * inv);
        *(uint2*)(ob + cb * 16) = st;
      }
    }
  }
}

// ---------------- launch ----------------
extern "C" void kernel_launch(void* const* d_in, const int* in_sizes, int n_in,
                              void* d_out, int out_size, void* d_ws, size_t ws_size,
                              hipStream_t stream) {
  const float* Q  = (const float*)d_in[0];
  const float* K  = (const float*)d_in[1];
  const float* V  = (const float*)d_in[2];
  const float* Wq = (const float*)d_in[3];
  const float* bq = (const float*)d_in[4];
  const float* Wk = (const float*)d_in[5];
  const float* bk = (const float*)d_in[6];
  const float* Wv = (const float*)d_in[7];
  const float* bv = (const float*)d_in[8];
  const float* Wo = (const float*)d_in[9];
  const float* bo = (const float*)d_in[10];
  float* out = (float*)d_out;
  ushort* ws = (ushort*)d_ws;

  const size_t WN = (size_t)1024 * 1024;       // weight elems
  const size_t PN = (size_t)B_ * S_ * DM;      // activation elems (8.39M)
  ushort* wT  = ws;                             // wq/wk/wv/wo transposed, contiguous
  ushort* woT = ws + 3 * WN;
  ushort* qws = ws + 4 * WN;
  ushort* kws = qws + PN;
  ushort* ows = kws + PN;
  ushort* vt  = (ushort*)d_out;  // V^T scratch in d_out (bf16 16.8MB < fp32 33.5MB); overwritten by final GEMM

  transposeW4<<<dim3(256, 4), 256, 0, stream>>>(Wq, Wk, Wv, Wo, wT);

  // fused Q/K/V projections (bench-level winner per R7/R9 post-mortems)
  gemm_qkv<<<dim3(64, 8, 3), 256, 0, stream>>>(Q, K, V, wT, bq, bk, bv, qws, kws, vt);

  attn<<<BH * 8, 512, 0, stream>>>(qws, kws, vt, ows);

  gemm_out<<<dim3(64, 8), 256, 0, stream>>>(ows, woT, bo, out);
}